// Round 4
// baseline (256.610 us; speedup 1.0000x reference)
//
#include <hip/hip_runtime.h>
#include <hip/hip_bf16.h>
#include <math.h>

#define N_NODES 50000
#define N_EDGES 800000
#define CAP 32          // bucket row = 32 ushorts = exactly one 64B line
#define MAX_OVF 8192    // overflow list; P(deg>32)~1e-4 -> ~5 nodes, ~50 edges

// Two-phase binning:
#define NBIN 196                    // ceil(N_NODES/256) coarse bins of 256 nodes
#define KA_BLOCKS 256               // binning blocks
#define EPB (N_EDGES / KA_BLOCKS)   // 3125 edges per block (exact)
#define SUBCAP 48                   // per-(bin,block) arena cap: mean 16, sigma 4 -> 8 sigma

#define UV_BLOCKS 1024
#define W2_BLOCKS 16
#define P1_GRID (KA_BLOCKS + UV_BLOCKS + W2_BLOCKS)

typedef __bf16 bf16x8 __attribute__((ext_vector_type(8)));
typedef float f32x4 __attribute__((ext_vector_type(4)));

// ---------------------------------------------------------------------------
// Phase 1 (fused, all independent work):
//   blocks [0,256):     edge binning -> per-(bin,block) arena chunks (LDS
//                       histogram+rank; zero global atomics common path).
//   blocks [256,1280):  U[i]=(W1a-W1b)x_i+b1 (fp32) ; V[j]=W1b x_j -> bf16.
//                       V bf16: halves the node_kernel gather bytes AND gives
//                       4-lane/64B-line coalescing on the random row gather.
//   blocks [1280,1296): W2 -> bf16 hi + bf16 lo residual (B-side split kills
//                       the W2-quantization error that dominated absmax).
// cur[] poison-base trick: cur[0] untouched = base; cur[16] = ovf cursor;
// cur[32] = arena-overflow force-scan flag.
// ---------------------------------------------------------------------------
__global__ __launch_bounds__(256) void phase1_kernel(
    const float* __restrict__ x, const float* __restrict__ W1,
    const float* __restrict__ b1, const float* __restrict__ W2,
    const int* __restrict__ ei,
    float* __restrict__ U, __bf16* __restrict__ Vh,
    __bf16* __restrict__ w2hi, __bf16* __restrict__ w2lo,
    unsigned* __restrict__ arena, unsigned* __restrict__ cntA,
    unsigned* __restrict__ cur, int2* __restrict__ ovf)
{
    __shared__ unsigned sh_hist[256];
    __shared__ unsigned sh_pack[EPB];        // src | dlow<<16 | bin<<24
    __shared__ unsigned short sh_rank[EPB];  // rank within (block,bin)

    const int blk = blockIdx.x;
    const int tid = threadIdx.x;

    if (blk < KA_BLOCKS) {
        // ---- edge binning ----
        sh_hist[tid] = 0;
        __syncthreads();
        const int e0 = blk * EPB;
        for (int i = tid; i < EPB; i += 256) {
            int s = ei[e0 + i];
            int d = ei[N_EDGES + e0 + i];
            unsigned bin = (unsigned)d >> 8;
            unsigned r = atomicAdd(&sh_hist[bin], 1u);
            sh_pack[i] = (unsigned)s | ((unsigned)(d & 255) << 16) | (bin << 24);
            sh_rank[i] = (unsigned short)r;
        }
        __syncthreads();
        if (tid < NBIN) cntA[tid * KA_BLOCKS + blk] = sh_hist[tid];
        const unsigned base = cur[0];
        for (int i = tid; i < EPB; i += 256) {
            unsigned p = sh_pack[i];
            unsigned r = sh_rank[i];
            unsigned bin = p >> 24;
            if (r < SUBCAP) {
                arena[((size_t)bin * KA_BLOCKS + blk) * SUBCAP + r] = p;
            } else {
                // arena overflow (statistically never): exact fallback
                atomicAdd(&cur[32], 1u);  // force node_kernel to scan ovf
                unsigned o = atomicAdd(&cur[16], 1u) - base;
                int d = (int)(bin * 256 + ((p >> 16) & 255u));
                int s = (int)(p & 0xFFFFu);
                if (o < MAX_OVF) ovf[o] = make_int2(d, s);
            }
        }
    } else if (blk < KA_BLOCKS + UV_BLOCKS) {
        // ---- U/V prep ----
        const int lane = tid & 63;
        const int ublk = blk - KA_BLOCKS;
        const int wave = (int)((ublk * 256 + tid) >> 6);
        const int nwav = UV_BLOCKS * 4;

        float wa[64], wb[64];
#pragma unroll
        for (int k4 = 0; k4 < 16; ++k4) {
            float4 pa = *(const float4*)(W1 + lane * 128 + k4 * 4);
            float4 pb = *(const float4*)(W1 + lane * 128 + 64 + k4 * 4);
            wa[k4 * 4 + 0] = pa.x - pb.x;  wb[k4 * 4 + 0] = pb.x;
            wa[k4 * 4 + 1] = pa.y - pb.y;  wb[k4 * 4 + 1] = pb.y;
            wa[k4 * 4 + 2] = pa.z - pb.z;  wb[k4 * 4 + 2] = pb.z;
            wa[k4 * 4 + 3] = pa.w - pb.w;  wb[k4 * 4 + 3] = pb.w;
        }
        const float bias = b1[lane];

        for (int i = wave; i < N_NODES; i += nwav) {
            float xv = x[i * 64 + lane];
            float u = bias, v = 0.f;
#pragma unroll
            for (int k = 0; k < 64; ++k) {
                float xk = __int_as_float(
                    __builtin_amdgcn_readlane(__float_as_int(xv), k));
                u = fmaf(wa[k], xk, u);
                v = fmaf(wb[k], xk, v);
            }
            U[i * 64 + lane] = u;
            Vh[i * 64 + lane] = (__bf16)v;
        }
    } else {
        const int i = (blk - KA_BLOCKS - UV_BLOCKS) * 256 + tid;
        if (i < 64 * 64) {
            float w = W2[i];
            __bf16 hi = (__bf16)w;
            w2hi[i] = hi;
            w2lo[i] = (__bf16)(w - (float)hi);
        }
    }
}

// ---------------------------------------------------------------------------
// Phase 2: one block per coarse bin, 1024 threads. Thread (part,chunk) drains
// quarter [part*n/4,(part+1)*n/4) of arena chunk 'chunk' (slot ORDER within a
// bucket row is irrelevant for max). Writes exact per-node counts.
// ---------------------------------------------------------------------------
__global__ __launch_bounds__(1024) void bucket_kernel(
    const unsigned* __restrict__ arena, const unsigned* __restrict__ cntA,
    unsigned* __restrict__ counts, unsigned short* __restrict__ buckets,
    unsigned* __restrict__ cur, int2* __restrict__ ovf)
{
    __shared__ unsigned lcnt[256];
    const int bin = blockIdx.x;
    const int tid = threadIdx.x;
    if (tid < 256) lcnt[tid] = 0;
    __syncthreads();

    const unsigned base = cur[0];
    const int chunk = tid & 255;
    const int part  = tid >> 8;                        // 0..3
    unsigned n = cntA[(size_t)bin * KA_BLOCKS + chunk];
    if (n > SUBCAP) n = SUBCAP;                        // excess went to ovf
    const unsigned j0 = (n * (unsigned)part) >> 2;
    const unsigned j1 = (n * (unsigned)(part + 1)) >> 2;
    const unsigned* ch = arena + ((size_t)bin * KA_BLOCKS + chunk) * SUBCAP;

    for (unsigned j = j0; j < j1; ++j) {
        unsigned p = ch[j];
        unsigned dlow = (p >> 16) & 255u;
        unsigned s = p & 0xFFFFu;
        unsigned pos = atomicAdd(&lcnt[dlow], 1u);
        int d = bin * 256 + (int)dlow;
        if (pos < CAP) {
            buckets[(size_t)d * CAP + pos] = (unsigned short)s;
        } else {
            unsigned o = atomicAdd(&cur[16], 1u) - base;
            if (o < MAX_OVF) ovf[o] = make_int2(d, (int)s);
        }
    }
    __syncthreads();
    if (tid < 256) {
        const int node = bin * 256 + tid;
        if (node < N_NODES) counts[node] = lcnt[tid];
    }
}

// ---------------------------------------------------------------------------
// Tile compute: h=leaky(u + v(bf16)) fp32 -> A hi/lo bf16 frags; B = W2 split
// hi/lo bf16 -> 6 MFMAs per t-half pair (skip lo*lo ~ 2^-18): per tile
// 24 MFMAs. Masked max over rows 4q+r < lim, shfl-reduce over q, fold rm[4].
//   A: lane m+16q holds A[m][k]   B: lane n+16q holds W2[n][k]
//   D: lane holds D[4q+r][lane&15]
// ---------------------------------------------------------------------------
__device__ __forceinline__ void tile_mfma_max(
    const float4* __restrict__ uf4, const bf16x8* __restrict__ vv,
    const __bf16* __restrict__ w2hi, const __bf16* __restrict__ w2lo,
    int m, int q, int lim, float* __restrict__ rm)
{
    bf16x8 ahi[2], alo[2];
#pragma unroll
    for (int s = 0; s < 2; ++s) {
        const float4 a = uf4[2 * s], b = uf4[2 * s + 1];
        float uvv[8] = {a.x, a.y, a.z, a.w, b.x, b.y, b.z, b.w};
#pragma unroll
        for (int j = 0; j < 8; ++j) {
            float h = uvv[j] + (float)vv[s][j];
            h = fmaxf(h, 0.01f * h);                 // LeakyReLU
            __bf16 hb = (__bf16)h;
            ahi[s][j] = hb;
            alo[s][j] = (__bf16)(h - (float)hb);     // residual
        }
    }
#pragma unroll
    for (int t = 0; t < 4; ++t) {
        const bf16x8 b0h = *(const bf16x8*)(w2hi + (t * 16 + m) * 64 + q * 8);
        const bf16x8 b1h = *(const bf16x8*)(w2hi + (t * 16 + m) * 64 + 32 + q * 8);
        const bf16x8 b0l = *(const bf16x8*)(w2lo + (t * 16 + m) * 64 + q * 8);
        const bf16x8 b1l = *(const bf16x8*)(w2lo + (t * 16 + m) * 64 + 32 + q * 8);
        f32x4 acc = {0.f, 0.f, 0.f, 0.f};
        acc = __builtin_amdgcn_mfma_f32_16x16x32_bf16(ahi[0], b0h, acc, 0, 0, 0);
        acc = __builtin_amdgcn_mfma_f32_16x16x32_bf16(alo[0], b0h, acc, 0, 0, 0);
        acc = __builtin_amdgcn_mfma_f32_16x16x32_bf16(ahi[0], b0l, acc, 0, 0, 0);
        acc = __builtin_amdgcn_mfma_f32_16x16x32_bf16(ahi[1], b1h, acc, 0, 0, 0);
        acc = __builtin_amdgcn_mfma_f32_16x16x32_bf16(alo[1], b1h, acc, 0, 0, 0);
        acc = __builtin_amdgcn_mfma_f32_16x16x32_bf16(ahi[1], b1l, acc, 0, 0, 0);
        float v = -INFINITY;
#pragma unroll
        for (int r = 0; r < 4; ++r)
            if (4 * q + r < lim) v = fmaxf(v, acc[r]);   // mask garbage rows
        v = fmaxf(v, __shfl_xor(v, 16, 64));
        v = fmaxf(v, __shfl_xor(v, 32, 64));
        rm[t] = fmaxf(rm[t], v);
    }
}

// bf16 V row gather: lane(m,q) reads bytes [q*16,+16) and [64+q*16,+16) of a
// 128B row -> within one instruction the 4 q-lanes of a row cover one full
// 64B line (4-lane coalescing; fp32 rows only achieved 2-lane).
__device__ __forceinline__ void load_vh(const __bf16* __restrict__ Vh,
                                        unsigned si, int q, bf16x8* vv)
{
    const __bf16* b0 = Vh + (size_t)si * 64 + q * 8;
    vv[0] = *(const bf16x8*)b0;
    vv[1] = *(const bf16x8*)(b0 + 32);
}

// ---------------------------------------------------------------------------
// K3: wave per node, 2-deep software pipeline, now with TILE-1 PREFETCH:
// bucket entries 16+m share the 64B line with entry m (free), so tile-1 V
// rows for node B are issued during node A's compute (predicated on the
// wave-uniform cntB>16) — removes the serial ~500-900cy tile-1 chain that
// hit ~43% of nodes and could not be hidden at the 4-waves/SIMD register cap.
// Tile-1 is mask-limited (lim=deg-16) instead of dup-padded.
// Grid 1024 @ (256,4): R1 codegen (VGPR=64 arch, no spill).
// ---------------------------------------------------------------------------
__global__ __launch_bounds__(256, 4) void node_kernel(
    const unsigned* __restrict__ counts, const unsigned short* __restrict__ buckets,
    const int2* __restrict__ ovf,
    const float* __restrict__ U, const __bf16* __restrict__ Vh,
    const __bf16* __restrict__ w2hi, const __bf16* __restrict__ w2lo,
    const float* __restrict__ b2, float* __restrict__ out,
    const unsigned* __restrict__ cur)
{
    const int lane = threadIdx.x & 63;
    const int m    = lane & 15;
    const int q    = lane >> 4;
    const int wave = (int)((blockIdx.x * blockDim.x + threadIdx.x) >> 6);
    const int nwav = (int)((gridDim.x * blockDim.x) >> 6);

    const float b2v = b2[lane];
    const unsigned base  = cur[0];
    const unsigned force = cur[32] - base;   // arena-overflow force-scan flag
    const unsigned nou   = cur[16] - base;   // total ovf entries

    // ---- prologue: arm node A fully; arm meta for node B ----
    const int nA0 = wave;                        // wave < 4096 < N_NODES
    int pB = nA0 + nwav; if (pB >= N_NODES) pB = N_NODES - 1;

    unsigned cntA = counts[nA0];
    int bktA  = buckets[nA0 * CAP + m];
    int bkt2A = buckets[nA0 * CAP + 16 + m];
    float4 ufA[4];
    {
        const float* ub0 = U + (size_t)nA0 * 64 + q * 8;
        ufA[0] = ((const float4*)ub0)[0]; ufA[1] = ((const float4*)ub0)[1];
        ufA[2] = ((const float4*)(ub0 + 32))[0]; ufA[3] = ((const float4*)(ub0 + 32))[1];
    }
    unsigned cntB = counts[pB];
    int bktB  = buckets[pB * CAP + m];
    int bkt2B = buckets[pB * CAP + 16 + m];

    bf16x8 vA[2], v2A[2], vB[2], v2B[2];
    {
        unsigned usiA = (unsigned)bktA;
        if (usiA >= N_NODES) usiA = N_NODES - 1;   // poison-safe clamp
        load_vh(Vh, usiA, q, vA);
    }
    if (cntA > 16u) {
        unsigned usi2 = (unsigned)bkt2A;
        if (usi2 >= N_NODES) usi2 = N_NODES - 1;
        load_vh(Vh, usi2, q, v2A);
    }
    float4 ufB[4];
    {
        const float* ub0 = U + (size_t)pB * 64 + q * 8;
        ufB[0] = ((const float4*)ub0)[0]; ufB[1] = ((const float4*)ub0)[1];
        ufB[2] = ((const float4*)(ub0 + 32))[0]; ufB[3] = ((const float4*)(ub0 + 32))[1];
    }

    for (int n = nA0; n < N_NODES; n += nwav) {
        int pC = n + 2 * nwav; if (pC >= N_NODES) pC = N_NODES - 1;

        // (1) issue V tile-0 (and tile-1 if needed) for node B
        {
            unsigned usiB = (unsigned)bktB;
            if (usiB >= N_NODES) usiB = N_NODES - 1;
            load_vh(Vh, usiB, q, vB);
        }
        if (cntB > 16u) {
            unsigned usi2 = (unsigned)bkt2B;
            if (usi2 >= N_NODES) usi2 = N_NODES - 1;
            load_vh(Vh, usi2, q, v2B);
        }

        // (2) issue meta for node C
        unsigned cntC = counts[pC];
        int bktC  = buckets[pC * CAP + m];
        int bkt2C = buckets[pC * CAP + 16 + m];

        // (3) compute node A = n  (both tiles pre-armed)
        const unsigned c = cntA;
        const int deg = (c < CAP) ? (int)c : CAP;

        float rm[4] = {-INFINITY, -INFINITY, -INFINITY, -INFINITY};
        const int lim0 = (deg < 16) ? deg : 16;
        tile_mfma_max(ufA, vA, w2hi, w2lo, m, q, lim0, rm);
        if (deg > 16)
            tile_mfma_max(ufA, v2A, w2hi, w2lo, m, q, deg - 16, rm);

        if (c > CAP || force != 0u) {   // exact-correctness fallback
            int no = (nou < MAX_OVF) ? (int)nou : MAX_OVF;
            for (int o = 0; o < no; ++o) {
                const int2 ds = ovf[o];
                if (ds.x != n) continue;
                bf16x8 vo[2];
                load_vh(Vh, (unsigned)ds.y, q, vo);
                tile_mfma_max(ufA, vo, w2hi, w2lo, m, q, 16, rm);
            }
        }

        const float sel = (q == 0) ? rm[0] : (q == 1) ? rm[1]
                        : (q == 2) ? rm[2] : rm[3];      // col == lane
        out[(size_t)n * 64 + lane] = (c != 0u) ? tanhf(sel + b2v) : 0.f;

        // (4) rotate pipeline state; issue U for next B
        cntA = cntB; cntB = cntC;
        bktB = bktC; bkt2B = bkt2C;
#pragma unroll
        for (int i = 0; i < 4; ++i) ufA[i] = ufB[i];
#pragma unroll
        for (int i = 0; i < 2; ++i) { vA[i] = vB[i]; v2A[i] = v2B[i]; }
        {
            const float* ub0 = U + (size_t)pC * 64 + q * 8;   // next iter's B == pC
            ufB[0] = ((const float4*)ub0)[0]; ufB[1] = ((const float4*)ub0)[1];
            ufB[2] = ((const float4*)(ub0 + 32))[0]; ufB[3] = ((const float4*)(ub0 + 32))[1];
        }
    }
}

// ---------------------------------------------------------------------------
extern "C" void kernel_launch(void* const* d_in, const int* in_sizes, int n_in,
                              void* d_out, int out_size, void* d_ws, size_t ws_size,
                              hipStream_t stream)
{
    const float* x  = (const float*)d_in[0];
    const int*   ei = (const int*)d_in[1];
    const float* W1 = (const float*)d_in[2];
    const float* b1 = (const float*)d_in[3];
    const float* W2 = (const float*)d_in[4];
    const float* b2 = (const float*)d_in[5];
    float* out = (float*)d_out;

    char* p = (char*)d_ws;
    float* U = (float*)p;                  p += (size_t)N_NODES * 64 * 4;
    __bf16* Vh = (__bf16*)p;               p += (size_t)N_NODES * 64 * 2;
    unsigned* arena = (unsigned*)p;        p += (size_t)NBIN * KA_BLOCKS * SUBCAP * 4;
    unsigned short* buckets = (unsigned short*)p;
                                           p += (size_t)N_NODES * CAP * 2;
    __bf16* w2hi = (__bf16*)p;             p += 64 * 64 * 2;
    __bf16* w2lo = (__bf16*)p;             p += 64 * 64 * 2;
    unsigned* cntA = (unsigned*)p;         p += (size_t)NBIN * KA_BLOCKS * 4;
    unsigned* counts = (unsigned*)p;       p += (size_t)((N_NODES + 63) / 64) * 64 * 4;
    unsigned* cur = (unsigned*)p;          p += 64 * 4;
    int2* ovf = (int2*)p;                  p += (size_t)MAX_OVF * 8;

    phase1_kernel<<<P1_GRID, 256, 0, stream>>>(x, W1, b1, W2, ei,
                                               U, Vh, w2hi, w2lo,
                                               arena, cntA, cur, ovf);
    bucket_kernel<<<NBIN, 1024, 0, stream>>>(arena, cntA, counts, buckets, cur, ovf);
    node_kernel<<<1024, 256, 0, stream>>>(counts, buckets, ovf,
                                          U, Vh, w2hi, w2lo, b2, out, cur);
}

// Round 5
// 220.991 us; speedup vs baseline: 1.1612x; 1.1612x over previous
//
#include <hip/hip_runtime.h>
#include <hip/hip_bf16.h>
#include <math.h>

#define N_NODES 50000
#define N_EDGES 800000
#define CAP 32          // bucket row = 32 ushorts = exactly one 64B line
#define MAX_OVF 8192    // overflow list; P(deg>32)~1e-4 -> ~5 nodes, ~50 edges

// Two-phase binning:
#define NBIN 196                    // ceil(N_NODES/256) coarse bins of 256 nodes
#define KA_BLOCKS 256               // binning blocks
#define EPB (N_EDGES / KA_BLOCKS)   // 3125 edges per block (exact)
#define SUBCAP 48                   // per-(bin,block) arena cap: mean 16, sigma 4 -> 8 sigma

#define UV_BLOCKS 1024
#define W2_BLOCKS 16
#define P1_GRID (KA_BLOCKS + UV_BLOCKS + W2_BLOCKS)

typedef __bf16 bf16x8 __attribute__((ext_vector_type(8)));
typedef float f32x4 __attribute__((ext_vector_type(4)));

// ---------------------------------------------------------------------------
// Phase 1 (fused, all independent work):
//   blocks [0,256):     edge binning -> per-(bin,block) arena chunks (LDS
//                       histogram+rank; zero global atomics common path).
//   blocks [256,1280):  U[i]=(W1a-W1b)x_i+b1 (fp32) ; V[j]=W1b x_j -> bf16.
//   blocks [1280,1296): W2 -> bf16 hi + bf16 lo residual.
// cur[] poison-base trick: cur[0] untouched = base; cur[16] = ovf cursor;
// cur[32] = arena-overflow force-scan flag.
// ---------------------------------------------------------------------------
__global__ __launch_bounds__(256) void phase1_kernel(
    const float* __restrict__ x, const float* __restrict__ W1,
    const float* __restrict__ b1, const float* __restrict__ W2,
    const int* __restrict__ ei,
    float* __restrict__ U, __bf16* __restrict__ Vh,
    __bf16* __restrict__ w2hi, __bf16* __restrict__ w2lo,
    unsigned* __restrict__ arena, unsigned* __restrict__ cntA,
    unsigned* __restrict__ cur, int2* __restrict__ ovf)
{
    __shared__ unsigned sh_hist[256];
    __shared__ unsigned sh_pack[EPB];        // src | dlow<<16 | bin<<24
    __shared__ unsigned short sh_rank[EPB];  // rank within (block,bin)

    const int blk = blockIdx.x;
    const int tid = threadIdx.x;

    if (blk < KA_BLOCKS) {
        // ---- edge binning ----
        sh_hist[tid] = 0;
        __syncthreads();
        const int e0 = blk * EPB;
        for (int i = tid; i < EPB; i += 256) {
            int s = ei[e0 + i];
            int d = ei[N_EDGES + e0 + i];
            unsigned bin = (unsigned)d >> 8;
            unsigned r = atomicAdd(&sh_hist[bin], 1u);
            sh_pack[i] = (unsigned)s | ((unsigned)(d & 255) << 16) | (bin << 24);
            sh_rank[i] = (unsigned short)r;
        }
        __syncthreads();
        if (tid < NBIN) cntA[tid * KA_BLOCKS + blk] = sh_hist[tid];
        const unsigned base = cur[0];
        for (int i = tid; i < EPB; i += 256) {
            unsigned p = sh_pack[i];
            unsigned r = sh_rank[i];
            unsigned bin = p >> 24;
            if (r < SUBCAP) {
                arena[((size_t)bin * KA_BLOCKS + blk) * SUBCAP + r] = p;
            } else {
                // arena overflow (statistically never): exact fallback
                atomicAdd(&cur[32], 1u);  // force node_kernel to scan ovf
                unsigned o = atomicAdd(&cur[16], 1u) - base;
                int d = (int)(bin * 256 + ((p >> 16) & 255u));
                int s = (int)(p & 0xFFFFu);
                if (o < MAX_OVF) ovf[o] = make_int2(d, s);
            }
        }
    } else if (blk < KA_BLOCKS + UV_BLOCKS) {
        // ---- U/V prep ----
        const int lane = tid & 63;
        const int ublk = blk - KA_BLOCKS;
        const int wave = (int)((ublk * 256 + tid) >> 6);
        const int nwav = UV_BLOCKS * 4;

        float wa[64], wb[64];
#pragma unroll
        for (int k4 = 0; k4 < 16; ++k4) {
            float4 pa = *(const float4*)(W1 + lane * 128 + k4 * 4);
            float4 pb = *(const float4*)(W1 + lane * 128 + 64 + k4 * 4);
            wa[k4 * 4 + 0] = pa.x - pb.x;  wb[k4 * 4 + 0] = pb.x;
            wa[k4 * 4 + 1] = pa.y - pb.y;  wb[k4 * 4 + 1] = pb.y;
            wa[k4 * 4 + 2] = pa.z - pb.z;  wb[k4 * 4 + 2] = pb.z;
            wa[k4 * 4 + 3] = pa.w - pb.w;  wb[k4 * 4 + 3] = pb.w;
        }
        const float bias = b1[lane];

        for (int i = wave; i < N_NODES; i += nwav) {
            float xv = x[i * 64 + lane];
            float u = bias, v = 0.f;
#pragma unroll
            for (int k = 0; k < 64; ++k) {
                float xk = __int_as_float(
                    __builtin_amdgcn_readlane(__float_as_int(xv), k));
                u = fmaf(wa[k], xk, u);
                v = fmaf(wb[k], xk, v);
            }
            U[i * 64 + lane] = u;
            Vh[i * 64 + lane] = (__bf16)v;
        }
    } else {
        const int i = (blk - KA_BLOCKS - UV_BLOCKS) * 256 + tid;
        if (i < 64 * 64) {
            float w = W2[i];
            __bf16 hi = (__bf16)w;
            w2hi[i] = hi;
            w2lo[i] = (__bf16)(w - (float)hi);
        }
    }
}

// ---------------------------------------------------------------------------
// Phase 2: one block per coarse bin, 1024 threads. Thread (part,chunk) drains
// quarter [part*n/4,(part+1)*n/4) of arena chunk 'chunk' (slot ORDER within a
// bucket row is irrelevant for max). Writes exact per-node counts.
// ---------------------------------------------------------------------------
__global__ __launch_bounds__(1024) void bucket_kernel(
    const unsigned* __restrict__ arena, const unsigned* __restrict__ cntA,
    unsigned* __restrict__ counts, unsigned short* __restrict__ buckets,
    unsigned* __restrict__ cur, int2* __restrict__ ovf)
{
    __shared__ unsigned lcnt[256];
    const int bin = blockIdx.x;
    const int tid = threadIdx.x;
    if (tid < 256) lcnt[tid] = 0;
    __syncthreads();

    const unsigned base = cur[0];
    const int chunk = tid & 255;
    const int part  = tid >> 8;                        // 0..3
    unsigned n = cntA[(size_t)bin * KA_BLOCKS + chunk];
    if (n > SUBCAP) n = SUBCAP;                        // excess went to ovf
    const unsigned j0 = (n * (unsigned)part) >> 2;
    const unsigned j1 = (n * (unsigned)(part + 1)) >> 2;
    const unsigned* ch = arena + ((size_t)bin * KA_BLOCKS + chunk) * SUBCAP;

    for (unsigned j = j0; j < j1; ++j) {
        unsigned p = ch[j];
        unsigned dlow = (p >> 16) & 255u;
        unsigned s = p & 0xFFFFu;
        unsigned pos = atomicAdd(&lcnt[dlow], 1u);
        int d = bin * 256 + (int)dlow;
        if (pos < CAP) {
            buckets[(size_t)d * CAP + pos] = (unsigned short)s;
        } else {
            unsigned o = atomicAdd(&cur[16], 1u) - base;
            if (o < MAX_OVF) ovf[o] = make_int2(d, (int)s);
        }
    }
    __syncthreads();
    if (tid < 256) {
        const int node = bin * 256 + tid;
        if (node < N_NODES) counts[node] = lcnt[tid];
    }
}

// ---------------------------------------------------------------------------
// Tile compute: h=leaky(u + v(bf16)) fp32 -> A hi/lo bf16 frags; B = W2 split
// hi/lo bf16 -> 6 MFMAs per tile (skip lo*lo ~ 2^-18). MFMAs are ordered so
// at most 2 B-fragments are live at once (R4's 4-live-B transient + prefetch
// state spilled; this version's live set is BELOW R1's, which compiled clean
// at VGPR=64).
//   A: lane m+16q holds A[m][k]   B: lane n+16q holds W2[n][k]
//   D: lane holds D[4q+r][lane&15]
// ---------------------------------------------------------------------------
__device__ __forceinline__ void tile_mfma_max(
    const float4* __restrict__ uf4, const bf16x8* __restrict__ vv,
    const __bf16* __restrict__ w2hi, const __bf16* __restrict__ w2lo,
    int m, int q, int lim, float* __restrict__ rm)
{
    bf16x8 ahi[2], alo[2];
#pragma unroll
    for (int s = 0; s < 2; ++s) {
        const float4 a = uf4[2 * s], b = uf4[2 * s + 1];
        float uvv[8] = {a.x, a.y, a.z, a.w, b.x, b.y, b.z, b.w};
#pragma unroll
        for (int j = 0; j < 8; ++j) {
            float h = uvv[j] + (float)vv[s][j];
            h = fmaxf(h, 0.01f * h);                 // LeakyReLU
            __bf16 hb = (__bf16)h;
            ahi[s][j] = hb;
            alo[s][j] = (__bf16)(h - (float)hb);     // residual
        }
    }
#pragma unroll
    for (int t = 0; t < 4; ++t) {
        f32x4 acc = {0.f, 0.f, 0.f, 0.f};
        {
            const bf16x8 b0h = *(const bf16x8*)(w2hi + (t * 16 + m) * 64 + q * 8);
            acc = __builtin_amdgcn_mfma_f32_16x16x32_bf16(ahi[0], b0h, acc, 0, 0, 0);
            acc = __builtin_amdgcn_mfma_f32_16x16x32_bf16(alo[0], b0h, acc, 0, 0, 0);
        }
        {
            const bf16x8 b0l = *(const bf16x8*)(w2lo + (t * 16 + m) * 64 + q * 8);
            acc = __builtin_amdgcn_mfma_f32_16x16x32_bf16(ahi[0], b0l, acc, 0, 0, 0);
        }
        {
            const bf16x8 b1h = *(const bf16x8*)(w2hi + (t * 16 + m) * 64 + 32 + q * 8);
            acc = __builtin_amdgcn_mfma_f32_16x16x32_bf16(ahi[1], b1h, acc, 0, 0, 0);
            acc = __builtin_amdgcn_mfma_f32_16x16x32_bf16(alo[1], b1h, acc, 0, 0, 0);
        }
        {
            const bf16x8 b1l = *(const bf16x8*)(w2lo + (t * 16 + m) * 64 + 32 + q * 8);
            acc = __builtin_amdgcn_mfma_f32_16x16x32_bf16(ahi[1], b1l, acc, 0, 0, 0);
        }
        float v = -INFINITY;
#pragma unroll
        for (int r = 0; r < 4; ++r)
            if (4 * q + r < lim) v = fmaxf(v, acc[r]);   // mask garbage rows
        v = fmaxf(v, __shfl_xor(v, 16, 64));
        v = fmaxf(v, __shfl_xor(v, 32, 64));
        rm[t] = fmaxf(rm[t], v);
    }
}

// bf16 V row gather: the 4 q-lanes of one row cover a full 64B line per
// instruction (fp32 rows only achieved 2-lane/line).
__device__ __forceinline__ void load_vh(const __bf16* __restrict__ Vh,
                                        unsigned si, int q, bf16x8* vv)
{
    const __bf16* b0 = Vh + (size_t)si * 64 + q * 8;
    vv[0] = *(const bf16x8*)b0;
    vv[1] = *(const bf16x8*)(b0 + 32);
}

// ---------------------------------------------------------------------------
// K3: wave per node, 2-deep software pipeline — EXACT R1 structure (53 µs,
// VGPR=64, zero spill), with bf16 V (−16 state regs, half the gather bytes)
// and split-B tiles. NO tile-1 prefetch (R4's +34 regs spilled 333MB of
// scratch at the 4-wave/SIMD budget). Grid 1024 @ (256,4).
// ---------------------------------------------------------------------------
__global__ __launch_bounds__(256, 4) void node_kernel(
    const unsigned* __restrict__ counts, const unsigned short* __restrict__ buckets,
    const int2* __restrict__ ovf,
    const float* __restrict__ U, const __bf16* __restrict__ Vh,
    const __bf16* __restrict__ w2hi, const __bf16* __restrict__ w2lo,
    const float* __restrict__ b2, float* __restrict__ out,
    const unsigned* __restrict__ cur)
{
    const int lane = threadIdx.x & 63;
    const int m    = lane & 15;
    const int q    = lane >> 4;
    const int wave = (int)((blockIdx.x * blockDim.x + threadIdx.x) >> 6);
    const int nwav = (int)((gridDim.x * blockDim.x) >> 6);

    const float b2v = b2[lane];
    const unsigned base  = cur[0];
    const unsigned force = cur[32] - base;   // arena-overflow force-scan flag
    const unsigned nou   = cur[16] - base;   // total ovf entries

    // ---- prologue: arm node A fully; arm bkt/cnt for node B ----
    const int nA0 = wave;                        // wave < 4096 < N_NODES
    int pB = nA0 + nwav; if (pB >= N_NODES) pB = N_NODES - 1;

    unsigned cntA = counts[nA0];
    int      bktA = buckets[nA0 * CAP + m];
    float4 ufA[4];
    {
        const float* ub0 = U + (size_t)nA0 * 64 + q * 8;
        ufA[0] = ((const float4*)ub0)[0]; ufA[1] = ((const float4*)ub0)[1];
        ufA[2] = ((const float4*)(ub0 + 32))[0]; ufA[3] = ((const float4*)(ub0 + 32))[1];
    }
    unsigned cntB = counts[pB];
    int      bktB = buckets[pB * CAP + m];

    bf16x8 vA[2];
    {
        unsigned usiA = (unsigned)bktA;
        if (usiA >= N_NODES) usiA = N_NODES - 1;   // poison-safe clamp
        load_vh(Vh, usiA, q, vA);
    }
    float4 ufB[4];
    {
        const float* ub0 = U + (size_t)pB * 64 + q * 8;
        ufB[0] = ((const float4*)ub0)[0]; ufB[1] = ((const float4*)ub0)[1];
        ufB[2] = ((const float4*)(ub0 + 32))[0]; ufB[3] = ((const float4*)(ub0 + 32))[1];
    }

    for (int n = nA0; n < N_NODES; n += nwav) {
        int pC = n + 2 * nwav; if (pC >= N_NODES) pC = N_NODES - 1;

        // (1) issue V for node B (bktB arrived during previous compute)
        unsigned usiB = (unsigned)bktB;
        if (usiB >= N_NODES) usiB = N_NODES - 1;
        bf16x8 vB[2];
        load_vh(Vh, usiB, q, vB);

        // (2) issue bkt/cnt for node C
        unsigned cntC = counts[pC];
        int      bktC = buckets[pC * CAP + m];

        // (3) compute node A = n
        const unsigned c = cntA;
        const int deg = (c < CAP) ? (int)c : CAP;

        float rm[4] = {-INFINITY, -INFINITY, -INFINITY, -INFINITY};
        const int lim0 = (deg < 16) ? deg : 16;
        tile_mfma_max(ufA, vA, w2hi, w2lo, m, q, lim0, rm);   // tile 0 (pre-armed)

        for (int base16 = 16; base16 < deg; base16 += 16) {   // tile 1 (deg > 16)
            int el = base16 + m; if (el > deg - 1) el = deg - 1;   // dup-pad
            unsigned si = (unsigned)buckets[n * CAP + el];         // valid entry
            bf16x8 v4[2];
            load_vh(Vh, si, q, v4);
            tile_mfma_max(ufA, v4, w2hi, w2lo, m, q, 16, rm);
        }

        if (c > CAP || force != 0u) {   // exact-correctness fallback
            int no = (nou < MAX_OVF) ? (int)nou : MAX_OVF;
            for (int o = 0; o < no; ++o) {
                const int2 ds = ovf[o];
                if (ds.x != n) continue;
                bf16x8 vo[2];
                load_vh(Vh, (unsigned)ds.y, q, vo);
                tile_mfma_max(ufA, vo, w2hi, w2lo, m, q, 16, rm);
            }
        }

        const float sel = (q == 0) ? rm[0] : (q == 1) ? rm[1]
                        : (q == 2) ? rm[2] : rm[3];      // col == lane
        out[(size_t)n * 64 + lane] = (c != 0u) ? tanhf(sel + b2v) : 0.f;

        // (4) rotate pipeline state; issue U for next B
        cntA = cntB; cntB = cntC;
        bktB = bktC;
#pragma unroll
        for (int i = 0; i < 4; ++i) ufA[i] = ufB[i];
#pragma unroll
        for (int i = 0; i < 2; ++i) vA[i] = vB[i];
        {
            const float* ub0 = U + (size_t)pC * 64 + q * 8;   // next iter's B == pC
            ufB[0] = ((const float4*)ub0)[0]; ufB[1] = ((const float4*)ub0)[1];
            ufB[2] = ((const float4*)(ub0 + 32))[0]; ufB[3] = ((const float4*)(ub0 + 32))[1];
        }
    }
}

// ---------------------------------------------------------------------------
extern "C" void kernel_launch(void* const* d_in, const int* in_sizes, int n_in,
                              void* d_out, int out_size, void* d_ws, size_t ws_size,
                              hipStream_t stream)
{
    const float* x  = (const float*)d_in[0];
    const int*   ei = (const int*)d_in[1];
    const float* W1 = (const float*)d_in[2];
    const float* b1 = (const float*)d_in[3];
    const float* W2 = (const float*)d_in[4];
    const float* b2 = (const float*)d_in[5];
    float* out = (float*)d_out;

    char* p = (char*)d_ws;
    float* U = (float*)p;                  p += (size_t)N_NODES * 64 * 4;
    __bf16* Vh = (__bf16*)p;               p += (size_t)N_NODES * 64 * 2;
    unsigned* arena = (unsigned*)p;        p += (size_t)NBIN * KA_BLOCKS * SUBCAP * 4;
    unsigned short* buckets = (unsigned short*)p;
                                           p += (size_t)N_NODES * CAP * 2;
    __bf16* w2hi = (__bf16*)p;             p += 64 * 64 * 2;
    __bf16* w2lo = (__bf16*)p;             p += 64 * 64 * 2;
    unsigned* cntA = (unsigned*)p;         p += (size_t)NBIN * KA_BLOCKS * 4;
    unsigned* counts = (unsigned*)p;       p += (size_t)((N_NODES + 63) / 64) * 64 * 4;
    unsigned* cur = (unsigned*)p;          p += 64 * 4;
    int2* ovf = (int2*)p;                  p += (size_t)MAX_OVF * 8;

    phase1_kernel<<<P1_GRID, 256, 0, stream>>>(x, W1, b1, W2, ei,
                                               U, Vh, w2hi, w2lo,
                                               arena, cntA, cur, ovf);
    bucket_kernel<<<NBIN, 1024, 0, stream>>>(arena, cntA, counts, buckets, cur, ovf);
    node_kernel<<<1024, 256, 0, stream>>>(counts, buckets, ovf,
                                          U, Vh, w2hi, w2lo, b2, out, cur);
}

// Round 6
// 161.889 us; speedup vs baseline: 1.5851x; 1.3651x over previous
//
#include <hip/hip_runtime.h>
#include <hip/hip_bf16.h>
#include <math.h>

#define N_NODES 50000
#define N_EDGES 800000
#define CAP 32          // bucket row = 32 ushorts = exactly one 64B line
#define MAX_OVF 8192    // overflow list; P(deg>32)~1e-4 -> ~5 nodes, ~50 edges

// Two-phase binning:
#define NBIN 196                    // ceil(N_NODES/256) coarse bins of 256 nodes
#define KA_BLOCKS 256               // binning blocks
#define EPB (N_EDGES / KA_BLOCKS)   // 3125 edges per block (exact)
#define SUBCAP 48                   // per-(bin,block) arena cap: mean 16, sigma 4 -> 8 sigma

#define UV_BLOCKS 1024
#define W2_BLOCKS 16
#define P1_GRID (KA_BLOCKS + UV_BLOCKS + W2_BLOCKS)

typedef _Float16 f16x8 __attribute__((ext_vector_type(8)));
typedef float f32x4 __attribute__((ext_vector_type(4)));

// ---------------------------------------------------------------------------
// Phase 1 (fused, all independent work):
//   blocks [0,256):     edge binning -> per-(bin,block) arena chunks (LDS
//                       histogram+rank; zero global atomics common path).
//   blocks [256,1280):  U[i]=(W1a-W1b)x_i+b1 (fp32) ; V[j]=W1b x_j -> f16.
//                       f16 V: half the node gather bytes, 4-lane/64B-line
//                       coalescing, and 2^-11 rel err (vs bf16's 2^-8).
//   blocks [1280,1296): W2 -> f16 (10 mantissa bits: no hi/lo split needed —
//                       R4/R5's split-B 6-MFMA tile spilled 240-330MB scratch
//                       from 16 hoisted B-fragment transients).
// cur[] poison-base trick: cur[0] untouched = base; cur[16] = ovf cursor;
// cur[32] = arena-overflow force-scan flag.
// ---------------------------------------------------------------------------
__global__ __launch_bounds__(256) void phase1_kernel(
    const float* __restrict__ x, const float* __restrict__ W1,
    const float* __restrict__ b1, const float* __restrict__ W2,
    const int* __restrict__ ei,
    float* __restrict__ U, _Float16* __restrict__ Vh,
    _Float16* __restrict__ w2f,
    unsigned* __restrict__ arena, unsigned* __restrict__ cntA,
    unsigned* __restrict__ cur, int2* __restrict__ ovf)
{
    __shared__ unsigned sh_hist[256];
    __shared__ unsigned sh_pack[EPB];        // src | dlow<<16 | bin<<24
    __shared__ unsigned short sh_rank[EPB];  // rank within (block,bin)

    const int blk = blockIdx.x;
    const int tid = threadIdx.x;

    if (blk < KA_BLOCKS) {
        // ---- edge binning ----
        sh_hist[tid] = 0;
        __syncthreads();
        const int e0 = blk * EPB;
        for (int i = tid; i < EPB; i += 256) {
            int s = ei[e0 + i];
            int d = ei[N_EDGES + e0 + i];
            unsigned bin = (unsigned)d >> 8;
            unsigned r = atomicAdd(&sh_hist[bin], 1u);
            sh_pack[i] = (unsigned)s | ((unsigned)(d & 255) << 16) | (bin << 24);
            sh_rank[i] = (unsigned short)r;
        }
        __syncthreads();
        if (tid < NBIN) cntA[tid * KA_BLOCKS + blk] = sh_hist[tid];
        const unsigned base = cur[0];
        for (int i = tid; i < EPB; i += 256) {
            unsigned p = sh_pack[i];
            unsigned r = sh_rank[i];
            unsigned bin = p >> 24;
            if (r < SUBCAP) {
                arena[((size_t)bin * KA_BLOCKS + blk) * SUBCAP + r] = p;
            } else {
                // arena overflow (statistically never): exact fallback
                atomicAdd(&cur[32], 1u);  // force node_kernel to scan ovf
                unsigned o = atomicAdd(&cur[16], 1u) - base;
                int d = (int)(bin * 256 + ((p >> 16) & 255u));
                int s = (int)(p & 0xFFFFu);
                if (o < MAX_OVF) ovf[o] = make_int2(d, s);
            }
        }
    } else if (blk < KA_BLOCKS + UV_BLOCKS) {
        // ---- U/V prep ----
        const int lane = tid & 63;
        const int ublk = blk - KA_BLOCKS;
        const int wave = (int)((ublk * 256 + tid) >> 6);
        const int nwav = UV_BLOCKS * 4;

        float wa[64], wb[64];
#pragma unroll
        for (int k4 = 0; k4 < 16; ++k4) {
            float4 pa = *(const float4*)(W1 + lane * 128 + k4 * 4);
            float4 pb = *(const float4*)(W1 + lane * 128 + 64 + k4 * 4);
            wa[k4 * 4 + 0] = pa.x - pb.x;  wb[k4 * 4 + 0] = pb.x;
            wa[k4 * 4 + 1] = pa.y - pb.y;  wb[k4 * 4 + 1] = pb.y;
            wa[k4 * 4 + 2] = pa.z - pb.z;  wb[k4 * 4 + 2] = pb.z;
            wa[k4 * 4 + 3] = pa.w - pb.w;  wb[k4 * 4 + 3] = pb.w;
        }
        const float bias = b1[lane];

        for (int i = wave; i < N_NODES; i += nwav) {
            float xv = x[i * 64 + lane];
            float u = bias, v = 0.f;
#pragma unroll
            for (int k = 0; k < 64; ++k) {
                float xk = __int_as_float(
                    __builtin_amdgcn_readlane(__float_as_int(xv), k));
                u = fmaf(wa[k], xk, u);
                v = fmaf(wb[k], xk, v);
            }
            U[i * 64 + lane] = u;
            Vh[i * 64 + lane] = (_Float16)v;
        }
    } else {
        const int i = (blk - KA_BLOCKS - UV_BLOCKS) * 256 + tid;
        if (i < 64 * 64) w2f[i] = (_Float16)W2[i];
    }
}

// ---------------------------------------------------------------------------
// Phase 2: one block per coarse bin, 1024 threads. Thread (part,chunk) drains
// quarter [part*n/4,(part+1)*n/4) of arena chunk 'chunk' (slot ORDER within a
// bucket row is irrelevant for max). Writes exact per-node counts.
// ---------------------------------------------------------------------------
__global__ __launch_bounds__(1024) void bucket_kernel(
    const unsigned* __restrict__ arena, const unsigned* __restrict__ cntA,
    unsigned* __restrict__ counts, unsigned short* __restrict__ buckets,
    unsigned* __restrict__ cur, int2* __restrict__ ovf)
{
    __shared__ unsigned lcnt[256];
    const int bin = blockIdx.x;
    const int tid = threadIdx.x;
    if (tid < 256) lcnt[tid] = 0;
    __syncthreads();

    const unsigned base = cur[0];
    const int chunk = tid & 255;
    const int part  = tid >> 8;                        // 0..3
    unsigned n = cntA[(size_t)bin * KA_BLOCKS + chunk];
    if (n > SUBCAP) n = SUBCAP;                        // excess went to ovf
    const unsigned j0 = (n * (unsigned)part) >> 2;
    const unsigned j1 = (n * (unsigned)(part + 1)) >> 2;
    const unsigned* ch = arena + ((size_t)bin * KA_BLOCKS + chunk) * SUBCAP;

    for (unsigned j = j0; j < j1; ++j) {
        unsigned p = ch[j];
        unsigned dlow = (p >> 16) & 255u;
        unsigned s = p & 0xFFFFu;
        unsigned pos = atomicAdd(&lcnt[dlow], 1u);
        int d = bin * 256 + (int)dlow;
        if (pos < CAP) {
            buckets[(size_t)d * CAP + pos] = (unsigned short)s;
        } else {
            unsigned o = atomicAdd(&cur[16], 1u) - base;
            if (o < MAX_OVF) ovf[o] = make_int2(d, (int)s);
        }
    }
    __syncthreads();
    if (tid < 256) {
        const int node = bin * 256 + tid;
        if (node < N_NODES) counts[node] = lcnt[tid];
    }
}

// ---------------------------------------------------------------------------
// Tile compute (f16): h=leaky(u + v(f16)) fp32 -> A hi/lo f16 frags; B = W2
// single f16 -> 4 MFMAs per t (EXACT R1 register shape, the largest tile that
// compiles clean at the 4-wave/SIMD budget; f16's 10 mantissa bits make the
// B-side split unnecessary). Masked max over rows 4q+r < lim, shfl-reduce.
//   A: lane m+16q holds A[m][k]   B: lane n+16q holds W2[n][k]
//   D: lane holds D[4q+r][lane&15]
// ---------------------------------------------------------------------------
__device__ __forceinline__ void tile_mfma_max(
    const float4* __restrict__ uf4, const f16x8* __restrict__ vv,
    const _Float16* __restrict__ w2f, int m, int q, int lim,
    float* __restrict__ rm)
{
    f16x8 ahi[2], alo[2];
#pragma unroll
    for (int s = 0; s < 2; ++s) {
        const float4 a = uf4[2 * s], b = uf4[2 * s + 1];
        float uvv[8] = {a.x, a.y, a.z, a.w, b.x, b.y, b.z, b.w};
#pragma unroll
        for (int j = 0; j < 8; ++j) {
            float h = uvv[j] + (float)vv[s][j];
            h = fmaxf(h, 0.01f * h);                 // LeakyReLU
            _Float16 hb = (_Float16)h;
            ahi[s][j] = hb;
            alo[s][j] = (_Float16)(h - (float)hb);   // residual
        }
    }
#pragma unroll
    for (int t = 0; t < 4; ++t) {
        const f16x8 b0 = *(const f16x8*)(w2f + (t * 16 + m) * 64 + q * 8);
        const f16x8 b1 = *(const f16x8*)(w2f + (t * 16 + m) * 64 + 32 + q * 8);
        f32x4 acc = {0.f, 0.f, 0.f, 0.f};
        acc = __builtin_amdgcn_mfma_f32_16x16x32_f16(ahi[0], b0, acc, 0, 0, 0);
        acc = __builtin_amdgcn_mfma_f32_16x16x32_f16(alo[0], b0, acc, 0, 0, 0);
        acc = __builtin_amdgcn_mfma_f32_16x16x32_f16(ahi[1], b1, acc, 0, 0, 0);
        acc = __builtin_amdgcn_mfma_f32_16x16x32_f16(alo[1], b1, acc, 0, 0, 0);
        float v = -INFINITY;
#pragma unroll
        for (int r = 0; r < 4; ++r)
            if (4 * q + r < lim) v = fmaxf(v, acc[r]);   // mask garbage rows
        v = fmaxf(v, __shfl_xor(v, 16, 64));
        v = fmaxf(v, __shfl_xor(v, 32, 64));
        rm[t] = fmaxf(rm[t], v);
    }
}

// f16 V row gather: the 4 q-lanes of one row cover a full 64B line per
// instruction (fp32 rows only achieved 2-lane/line).
__device__ __forceinline__ void load_vh(const _Float16* __restrict__ Vh,
                                        unsigned si, int q, f16x8* vv)
{
    const _Float16* b0 = Vh + (size_t)si * 64 + q * 8;
    vv[0] = *(const f16x8*)b0;
    vv[1] = *(const f16x8*)(b0 + 32);
}

// ---------------------------------------------------------------------------
// K3: wave per node, 2-deep software pipeline — R1 structure (the proven
// no-spill shape) with: f16 V (−8 state regs vs R1), single-f16-B tiles,
// and BUCKET-ENTRY prefetch for tile-1: entry 16+m shares the 64B line with
// entry m (free), carried through the pipeline as ONE register (R4's mistake
// was prefetching the 32-reg V payload — this prefetches only the address).
// Tile-1 is mask-limited (lim=deg-16): removes the bucket-load -> V-load
// dependent hop on the 43% of nodes with deg>16. Grid 1024 @ (256,4).
// ---------------------------------------------------------------------------
__global__ __launch_bounds__(256, 4) void node_kernel(
    const unsigned* __restrict__ counts, const unsigned short* __restrict__ buckets,
    const int2* __restrict__ ovf,
    const float* __restrict__ U, const _Float16* __restrict__ Vh,
    const _Float16* __restrict__ w2f, const float* __restrict__ b2,
    float* __restrict__ out, const unsigned* __restrict__ cur)
{
    const int lane = threadIdx.x & 63;
    const int m    = lane & 15;
    const int q    = lane >> 4;
    const int wave = (int)((blockIdx.x * blockDim.x + threadIdx.x) >> 6);
    const int nwav = (int)((gridDim.x * blockDim.x) >> 6);

    const float b2v = b2[lane];
    const unsigned base  = cur[0];
    const unsigned force = cur[32] - base;   // arena-overflow force-scan flag
    const unsigned nou   = cur[16] - base;   // total ovf entries

    // ---- prologue: arm node A fully; arm bkt/cnt for node B ----
    const int nA0 = wave;                        // wave < 4096 < N_NODES
    int pB = nA0 + nwav; if (pB >= N_NODES) pB = N_NODES - 1;

    unsigned cntA = counts[nA0];
    int bktA  = buckets[nA0 * CAP + m];
    int bkt2A = buckets[nA0 * CAP + 16 + m];     // same 64B line: free
    float4 ufA[4];
    {
        const float* ub0 = U + (size_t)nA0 * 64 + q * 8;
        ufA[0] = ((const float4*)ub0)[0]; ufA[1] = ((const float4*)ub0)[1];
        ufA[2] = ((const float4*)(ub0 + 32))[0]; ufA[3] = ((const float4*)(ub0 + 32))[1];
    }
    unsigned cntB = counts[pB];
    int bktB  = buckets[pB * CAP + m];
    int bkt2B = buckets[pB * CAP + 16 + m];

    f16x8 vA[2];
    {
        unsigned usiA = (unsigned)bktA;
        if (usiA >= N_NODES) usiA = N_NODES - 1;   // poison-safe clamp
        load_vh(Vh, usiA, q, vA);
    }
    float4 ufB[4];
    {
        const float* ub0 = U + (size_t)pB * 64 + q * 8;
        ufB[0] = ((const float4*)ub0)[0]; ufB[1] = ((const float4*)ub0)[1];
        ufB[2] = ((const float4*)(ub0 + 32))[0]; ufB[3] = ((const float4*)(ub0 + 32))[1];
    }

    for (int n = nA0; n < N_NODES; n += nwav) {
        int pC = n + 2 * nwav; if (pC >= N_NODES) pC = N_NODES - 1;

        // (1) issue V for node B (bktB arrived during previous compute)
        unsigned usiB = (unsigned)bktB;
        if (usiB >= N_NODES) usiB = N_NODES - 1;
        f16x8 vB[2];
        load_vh(Vh, usiB, q, vB);

        // (2) issue bkt/cnt for node C
        unsigned cntC = counts[pC];
        int bktC  = buckets[pC * CAP + m];
        int bkt2C = buckets[pC * CAP + 16 + m];

        // (3) compute node A = n
        const unsigned c = cntA;
        const int deg = (c < CAP) ? (int)c : CAP;

        float rm[4] = {-INFINITY, -INFINITY, -INFINITY, -INFINITY};
        const int lim0 = (deg < 16) ? deg : 16;
        tile_mfma_max(ufA, vA, w2f, m, q, lim0, rm);      // tile 0 (pre-armed)

        if (deg > 16) {                                   // tile 1: addr pre-armed
            unsigned si2 = (unsigned)bkt2A;               // entry 16+m; garbage
            if (si2 >= N_NODES) si2 = N_NODES - 1;        // rows masked by lim
            f16x8 v2[2];
            load_vh(Vh, si2, q, v2);
            tile_mfma_max(ufA, v2, w2f, m, q, deg - 16, rm);
        }

        if (c > CAP || force != 0u) {   // exact-correctness fallback
            int no = (nou < MAX_OVF) ? (int)nou : MAX_OVF;
            for (int o = 0; o < no; ++o) {
                const int2 ds = ovf[o];
                if (ds.x != n) continue;
                f16x8 vo[2];
                load_vh(Vh, (unsigned)ds.y, q, vo);
                tile_mfma_max(ufA, vo, w2f, m, q, 16, rm);
            }
        }

        const float sel = (q == 0) ? rm[0] : (q == 1) ? rm[1]
                        : (q == 2) ? rm[2] : rm[3];      // col == lane
        out[(size_t)n * 64 + lane] = (c != 0u) ? tanhf(sel + b2v) : 0.f;

        // (4) rotate pipeline state; issue U for next B
        cntA = cntB; cntB = cntC;
        bktB = bktC; bkt2A = bkt2B; bkt2B = bkt2C;
#pragma unroll
        for (int i = 0; i < 4; ++i) ufA[i] = ufB[i];
#pragma unroll
        for (int i = 0; i < 2; ++i) vA[i] = vB[i];
        {
            const float* ub0 = U + (size_t)pC * 64 + q * 8;   // next iter's B == pC
            ufB[0] = ((const float4*)ub0)[0]; ufB[1] = ((const float4*)ub0)[1];
            ufB[2] = ((const float4*)(ub0 + 32))[0]; ufB[3] = ((const float4*)(ub0 + 32))[1];
        }
    }
}

// ---------------------------------------------------------------------------
extern "C" void kernel_launch(void* const* d_in, const int* in_sizes, int n_in,
                              void* d_out, int out_size, void* d_ws, size_t ws_size,
                              hipStream_t stream)
{
    const float* x  = (const float*)d_in[0];
    const int*   ei = (const int*)d_in[1];
    const float* W1 = (const float*)d_in[2];
    const float* b1 = (const float*)d_in[3];
    const float* W2 = (const float*)d_in[4];
    const float* b2 = (const float*)d_in[5];
    float* out = (float*)d_out;

    char* p = (char*)d_ws;
    float* U = (float*)p;                  p += (size_t)N_NODES * 64 * 4;
    _Float16* Vh = (_Float16*)p;           p += (size_t)N_NODES * 64 * 2;
    unsigned* arena = (unsigned*)p;        p += (size_t)NBIN * KA_BLOCKS * SUBCAP * 4;
    unsigned short* buckets = (unsigned short*)p;
                                           p += (size_t)N_NODES * CAP * 2;
    _Float16* w2f = (_Float16*)p;          p += 64 * 64 * 2;
    unsigned* cntA = (unsigned*)p;         p += (size_t)NBIN * KA_BLOCKS * 4;
    unsigned* counts = (unsigned*)p;       p += (size_t)((N_NODES + 63) / 64) * 64 * 4;
    unsigned* cur = (unsigned*)p;          p += 64 * 4;
    int2* ovf = (int2*)p;                  p += (size_t)MAX_OVF * 8;

    phase1_kernel<<<P1_GRID, 256, 0, stream>>>(x, W1, b1, W2, ei,
                                               U, Vh, w2f,
                                               arena, cntA, cur, ovf);
    bucket_kernel<<<NBIN, 1024, 0, stream>>>(arena, cntA, counts, buckets, cur, ovf);
    node_kernel<<<1024, 256, 0, stream>>>(counts, buckets, ovf,
                                          U, Vh, w2f, b2, out, cur);
}

// Round 7
// 154.867 us; speedup vs baseline: 1.6570x; 1.0453x over previous
//
#include <hip/hip_runtime.h>
#include <hip/hip_bf16.h>
#include <math.h>

#define N_NODES 50000
#define N_EDGES 800000
#define CAP 32          // bucket row = 32 ushorts = exactly one 64B line
#define MAX_OVF 8192    // overflow list; P(deg>32)~1e-4 -> ~5 nodes, ~50 edges

// Two-phase binning:
#define NBIN 196                    // ceil(N_NODES/256) coarse bins of 256 nodes
#define KA_BLOCKS 256               // binning blocks
#define EPB (N_EDGES / KA_BLOCKS)   // 3125 edges per block (exact)
#define SUBCAP 48                   // per-(bin,block) arena cap: mean 16, sigma 4 -> 8 sigma

#define UV_BLOCKS 1024
#define W2_BLOCKS 16
#define P1_GRID (KA_BLOCKS + UV_BLOCKS + W2_BLOCKS)

typedef _Float16 f16x8 __attribute__((ext_vector_type(8)));
typedef float f32x4 __attribute__((ext_vector_type(4)));

// ---------------------------------------------------------------------------
// Phase 1 (fused, all independent work):
//   blocks [0,256):     edge binning -> per-(bin,block) arena chunks (LDS
//                       histogram+rank; zero global atomics common path).
//   blocks [256,1280):  U[i]=(W1a-W1b)x_i+b1 -> f16 ; V[j]=W1b x_j -> f16.
//                       BOTH f16: node repack becomes pure packed-f16 math
//                       (no fp32 adds, no cvt chains — R6 PMC: VALUBusy 53%
//                       was dominated by the fp32 repack), U state halves.
//   blocks [1280,1296): W2 -> f16.
// cur[] poison-base trick: cur[0] untouched = base; cur[16] = ovf cursor;
// cur[32] = arena-overflow force-scan flag.
// ---------------------------------------------------------------------------
__global__ __launch_bounds__(256) void phase1_kernel(
    const float* __restrict__ x, const float* __restrict__ W1,
    const float* __restrict__ b1, const float* __restrict__ W2,
    const int* __restrict__ ei,
    _Float16* __restrict__ Uh, _Float16* __restrict__ Vh,
    _Float16* __restrict__ w2f,
    unsigned* __restrict__ arena, unsigned* __restrict__ cntA,
    unsigned* __restrict__ cur, int2* __restrict__ ovf)
{
    __shared__ unsigned sh_hist[256];
    __shared__ unsigned sh_pack[EPB];        // src | dlow<<16 | bin<<24
    __shared__ unsigned short sh_rank[EPB];  // rank within (block,bin)

    const int blk = blockIdx.x;
    const int tid = threadIdx.x;

    if (blk < KA_BLOCKS) {
        // ---- edge binning ----
        sh_hist[tid] = 0;
        __syncthreads();
        const int e0 = blk * EPB;
        for (int i = tid; i < EPB; i += 256) {
            int s = ei[e0 + i];
            int d = ei[N_EDGES + e0 + i];
            unsigned bin = (unsigned)d >> 8;
            unsigned r = atomicAdd(&sh_hist[bin], 1u);
            sh_pack[i] = (unsigned)s | ((unsigned)(d & 255) << 16) | (bin << 24);
            sh_rank[i] = (unsigned short)r;
        }
        __syncthreads();
        if (tid < NBIN) cntA[tid * KA_BLOCKS + blk] = sh_hist[tid];
        const unsigned base = cur[0];
        for (int i = tid; i < EPB; i += 256) {
            unsigned p = sh_pack[i];
            unsigned r = sh_rank[i];
            unsigned bin = p >> 24;
            if (r < SUBCAP) {
                arena[((size_t)bin * KA_BLOCKS + blk) * SUBCAP + r] = p;
            } else {
                // arena overflow (statistically never): exact fallback
                atomicAdd(&cur[32], 1u);  // force node_kernel to scan ovf
                unsigned o = atomicAdd(&cur[16], 1u) - base;
                int d = (int)(bin * 256 + ((p >> 16) & 255u));
                int s = (int)(p & 0xFFFFu);
                if (o < MAX_OVF) ovf[o] = make_int2(d, s);
            }
        }
    } else if (blk < KA_BLOCKS + UV_BLOCKS) {
        // ---- U/V prep ----
        const int lane = tid & 63;
        const int ublk = blk - KA_BLOCKS;
        const int wave = (int)((ublk * 256 + tid) >> 6);
        const int nwav = UV_BLOCKS * 4;

        float wa[64], wb[64];
#pragma unroll
        for (int k4 = 0; k4 < 16; ++k4) {
            float4 pa = *(const float4*)(W1 + lane * 128 + k4 * 4);
            float4 pb = *(const float4*)(W1 + lane * 128 + 64 + k4 * 4);
            wa[k4 * 4 + 0] = pa.x - pb.x;  wb[k4 * 4 + 0] = pb.x;
            wa[k4 * 4 + 1] = pa.y - pb.y;  wb[k4 * 4 + 1] = pb.y;
            wa[k4 * 4 + 2] = pa.z - pb.z;  wb[k4 * 4 + 2] = pb.z;
            wa[k4 * 4 + 3] = pa.w - pb.w;  wb[k4 * 4 + 3] = pb.w;
        }
        const float bias = b1[lane];

        for (int i = wave; i < N_NODES; i += nwav) {
            float xv = x[i * 64 + lane];
            float u = bias, v = 0.f;
#pragma unroll
            for (int k = 0; k < 64; ++k) {
                float xk = __int_as_float(
                    __builtin_amdgcn_readlane(__float_as_int(xv), k));
                u = fmaf(wa[k], xk, u);
                v = fmaf(wb[k], xk, v);
            }
            Uh[i * 64 + lane] = (_Float16)u;
            Vh[i * 64 + lane] = (_Float16)v;
        }
    } else {
        const int i = (blk - KA_BLOCKS - UV_BLOCKS) * 256 + tid;
        if (i < 64 * 64) w2f[i] = (_Float16)W2[i];
    }
}

// ---------------------------------------------------------------------------
// Phase 2: one block per coarse bin, 1024 threads. Thread (part,chunk) drains
// quarter [part*n/4,(part+1)*n/4) of arena chunk 'chunk' (slot ORDER within a
// bucket row is irrelevant for max). Writes exact per-node counts.
// ---------------------------------------------------------------------------
__global__ __launch_bounds__(1024) void bucket_kernel(
    const unsigned* __restrict__ arena, const unsigned* __restrict__ cntA,
    unsigned* __restrict__ counts, unsigned short* __restrict__ buckets,
    unsigned* __restrict__ cur, int2* __restrict__ ovf)
{
    __shared__ unsigned lcnt[256];
    const int bin = blockIdx.x;
    const int tid = threadIdx.x;
    if (tid < 256) lcnt[tid] = 0;
    __syncthreads();

    const unsigned base = cur[0];
    const int chunk = tid & 255;
    const int part  = tid >> 8;                        // 0..3
    unsigned n = cntA[(size_t)bin * KA_BLOCKS + chunk];
    if (n > SUBCAP) n = SUBCAP;                        // excess went to ovf
    const unsigned j0 = (n * (unsigned)part) >> 2;
    const unsigned j1 = (n * (unsigned)(part + 1)) >> 2;
    const unsigned* ch = arena + ((size_t)bin * KA_BLOCKS + chunk) * SUBCAP;

    for (unsigned j = j0; j < j1; ++j) {
        unsigned p = ch[j];
        unsigned dlow = (p >> 16) & 255u;
        unsigned s = p & 0xFFFFu;
        unsigned pos = atomicAdd(&lcnt[dlow], 1u);
        int d = bin * 256 + (int)dlow;
        if (pos < CAP) {
            buckets[(size_t)d * CAP + pos] = (unsigned short)s;
        } else {
            unsigned o = atomicAdd(&cur[16], 1u) - base;
            if (o < MAX_OVF) ovf[o] = make_int2(d, (int)s);
        }
    }
    __syncthreads();
    if (tid < 256) {
        const int node = bin * 256 + tid;
        if (node < N_NODES) counts[node] = lcnt[tid];
    }
}

// ---------------------------------------------------------------------------
// Tile compute (all-f16): h = leaky(u+v) computed in PACKED f16 (pk_add /
// pk_mul / pk_max — no fp32, no cvt: h feeds the MFMA directly), single-f16
// A and B -> 2 MFMAs per output quadrant (8/tile, half of R6). Masked max
// over rows 4q+r < lim accumulates into rm[4]; the q-reduction (shfl) is
// hoisted OUT of the tile — done once per node by the caller.
//   A: lane m+16q holds A[m][k]   B: lane n+16q holds W2[n][k]
//   D: lane holds D[4q+r][lane&15]
// ---------------------------------------------------------------------------
__device__ __forceinline__ void tile_mfma_max(
    const f16x8* __restrict__ uh, const f16x8* __restrict__ vv,
    const _Float16* __restrict__ w2f, int m, int q, int lim,
    float* __restrict__ rm)
{
    f16x8 a[2];
#pragma unroll
    for (int s = 0; s < 2; ++s) {
        f16x8 h  = uh[s] + vv[s];
        f16x8 hs = h * (_Float16)0.01f;          // LeakyReLU = max(h, .01h)
#pragma unroll
        for (int j = 0; j < 8; ++j)
            a[s][j] = (h[j] > hs[j]) ? h[j] : hs[j];
    }
#pragma unroll
    for (int t = 0; t < 4; ++t) {
        const f16x8 b0 = *(const f16x8*)(w2f + (t * 16 + m) * 64 + q * 8);
        const f16x8 b1 = *(const f16x8*)(w2f + (t * 16 + m) * 64 + 32 + q * 8);
        f32x4 acc = {0.f, 0.f, 0.f, 0.f};
        acc = __builtin_amdgcn_mfma_f32_16x16x32_f16(a[0], b0, acc, 0, 0, 0);
        acc = __builtin_amdgcn_mfma_f32_16x16x32_f16(a[1], b1, acc, 0, 0, 0);
        float v = -INFINITY;
#pragma unroll
        for (int r = 0; r < 4; ++r)
            if (4 * q + r < lim) v = fmaxf(v, acc[r]);   // mask garbage rows
        rm[t] = fmaxf(rm[t], v);                 // q-reduce deferred to caller
    }
}

// f16 row gather (U and V share the layout): the 4 q-lanes of one row cover
// a full 64B line per instruction.
__device__ __forceinline__ void load_vh(const _Float16* __restrict__ Vh,
                                        unsigned si, int q, f16x8* vv)
{
    const _Float16* b0 = Vh + (size_t)si * 64 + q * 8;
    vv[0] = *(const f16x8*)b0;
    vv[1] = *(const f16x8*)(b0 + 32);
}

// tanh via hw exp + rcp: ~7 VALU vs libm's ~20+. |err| ~1e-6 (irrelevant at
// the 3e-3 accuracy scale of the f16 pipeline).
__device__ __forceinline__ float fast_tanh(float x)
{
    float xc = fminf(fmaxf(x, -12.f), 12.f);
    float e  = __expf(2.f * xc);
    return 1.f - 2.f * __builtin_amdgcn_rcpf(e + 1.f);
}

// ---------------------------------------------------------------------------
// K3: wave per node, 2-deep software pipeline — R1/R6 no-spill structure with
// all-f16 data (uh state 8 regs vs R6's 16-reg fp32 uf), 2-MFMA quadrants,
// bucket-entry (addr-only) tile-1 prefetch, deferred q-reduction, fast tanh.
// Targets R6 PMC: VALUBusy 53% / MfmaUtil 14% at reg-capped 4 waves/SIMD ->
// cut VALU issue per node ~2x. Grid 1024 @ (256,4).
// ---------------------------------------------------------------------------
__global__ __launch_bounds__(256, 4) void node_kernel(
    const unsigned* __restrict__ counts, const unsigned short* __restrict__ buckets,
    const int2* __restrict__ ovf,
    const _Float16* __restrict__ Uh, const _Float16* __restrict__ Vh,
    const _Float16* __restrict__ w2f, const float* __restrict__ b2,
    float* __restrict__ out, const unsigned* __restrict__ cur)
{
    const int lane = threadIdx.x & 63;
    const int m    = lane & 15;
    const int q    = lane >> 4;
    const int wave = (int)((blockIdx.x * blockDim.x + threadIdx.x) >> 6);
    const int nwav = (int)((gridDim.x * blockDim.x) >> 6);

    const float b2v = b2[lane];
    const unsigned base  = cur[0];
    const unsigned force = cur[32] - base;   // arena-overflow force-scan flag
    const unsigned nou   = cur[16] - base;   // total ovf entries

    // ---- prologue: arm node A fully; arm bkt/cnt for node B ----
    const int nA0 = wave;                        // wave < 4096 < N_NODES
    int pB = nA0 + nwav; if (pB >= N_NODES) pB = N_NODES - 1;

    unsigned cntA = counts[nA0];
    int bktA  = buckets[nA0 * CAP + m];
    int bkt2A = buckets[nA0 * CAP + 16 + m];     // same 64B line: free
    f16x8 uhA[2];
    load_vh(Uh, (unsigned)nA0, q, uhA);
    unsigned cntB = counts[pB];
    int bktB  = buckets[pB * CAP + m];
    int bkt2B = buckets[pB * CAP + 16 + m];

    f16x8 vA[2];
    {
        unsigned usiA = (unsigned)bktA;
        if (usiA >= N_NODES) usiA = N_NODES - 1;   // poison-safe clamp
        load_vh(Vh, usiA, q, vA);
    }
    f16x8 uhB[2];
    load_vh(Uh, (unsigned)pB, q, uhB);

    for (int n = nA0; n < N_NODES; n += nwav) {
        int pC = n + 2 * nwav; if (pC >= N_NODES) pC = N_NODES - 1;

        // (1) issue V for node B (bktB arrived during previous compute)
        unsigned usiB = (unsigned)bktB;
        if (usiB >= N_NODES) usiB = N_NODES - 1;
        f16x8 vB[2];
        load_vh(Vh, usiB, q, vB);

        // (2) issue bkt/cnt for node C
        unsigned cntC = counts[pC];
        int bktC  = buckets[pC * CAP + m];
        int bkt2C = buckets[pC * CAP + 16 + m];

        // (3) compute node A = n
        const unsigned c = cntA;
        const int deg = (c < CAP) ? (int)c : CAP;

        float rm[4] = {-INFINITY, -INFINITY, -INFINITY, -INFINITY};
        const int lim0 = (deg < 16) ? deg : 16;
        tile_mfma_max(uhA, vA, w2f, m, q, lim0, rm);      // tile 0 (pre-armed)

        if (deg > 16) {                                   // tile 1: addr pre-armed
            unsigned si2 = (unsigned)bkt2A;               // entry 16+m; garbage
            if (si2 >= N_NODES) si2 = N_NODES - 1;        // rows masked by lim
            f16x8 v2[2];
            load_vh(Vh, si2, q, v2);
            tile_mfma_max(uhA, v2, w2f, m, q, deg - 16, rm);
        }

        if (c > CAP || force != 0u) {   // exact-correctness fallback
            int no = (nou < MAX_OVF) ? (int)nou : MAX_OVF;
            for (int o = 0; o < no; ++o) {
                const int2 ds = ovf[o];
                if (ds.x != n) continue;
                f16x8 vo[2];
                load_vh(Vh, (unsigned)ds.y, q, vo);
                tile_mfma_max(uhA, vo, w2f, m, q, 16, rm);
            }
        }

        // deferred q-reduction (once per node, was per-tile in R6)
#pragma unroll
        for (int t = 0; t < 4; ++t) {
            rm[t] = fmaxf(rm[t], __shfl_xor(rm[t], 16, 64));
            rm[t] = fmaxf(rm[t], __shfl_xor(rm[t], 32, 64));
        }
        const float sel = (q == 0) ? rm[0] : (q == 1) ? rm[1]
                        : (q == 2) ? rm[2] : rm[3];      // col == lane
        out[(size_t)n * 64 + lane] = (c != 0u) ? fast_tanh(sel + b2v) : 0.f;

        // (4) rotate pipeline state; issue U for next B
        cntA = cntB; cntB = cntC;
        bktB = bktC; bkt2A = bkt2B; bkt2B = bkt2C;
#pragma unroll
        for (int i = 0; i < 2; ++i) { uhA[i] = uhB[i]; vA[i] = vB[i]; }
        load_vh(Uh, (unsigned)pC, q, uhB);               // next iter's B == pC
    }
}

// ---------------------------------------------------------------------------
extern "C" void kernel_launch(void* const* d_in, const int* in_sizes, int n_in,
                              void* d_out, int out_size, void* d_ws, size_t ws_size,
                              hipStream_t stream)
{
    const float* x  = (const float*)d_in[0];
    const int*   ei = (const int*)d_in[1];
    const float* W1 = (const float*)d_in[2];
    const float* b1 = (const float*)d_in[3];
    const float* W2 = (const float*)d_in[4];
    const float* b2 = (const float*)d_in[5];
    float* out = (float*)d_out;

    char* p = (char*)d_ws;
    _Float16* Uh = (_Float16*)p;           p += (size_t)N_NODES * 64 * 2;
    _Float16* Vh = (_Float16*)p;           p += (size_t)N_NODES * 64 * 2;
    unsigned* arena = (unsigned*)p;        p += (size_t)NBIN * KA_BLOCKS * SUBCAP * 4;
    unsigned short* buckets = (unsigned short*)p;
                                           p += (size_t)N_NODES * CAP * 2;
    _Float16* w2f = (_Float16*)p;          p += 64 * 64 * 2;
    unsigned* cntA = (unsigned*)p;         p += (size_t)NBIN * KA_BLOCKS * 4;
    unsigned* counts = (unsigned*)p;       p += (size_t)((N_NODES + 63) / 64) * 64 * 4;
    unsigned* cur = (unsigned*)p;          p += 64 * 4;
    int2* ovf = (int2*)p;                  p += (size_t)MAX_OVF * 8;

    phase1_kernel<<<P1_GRID, 256, 0, stream>>>(x, W1, b1, W2, ei,
                                               Uh, Vh, w2f,
                                               arena, cntA, cur, ovf);
    bucket_kernel<<<NBIN, 1024, 0, stream>>>(arena, cntA, counts, buckets, cur, ovf);
    node_kernel<<<1024, 256, 0, stream>>>(counts, buckets, ovf,
                                          Uh, Vh, w2f, b2, out, cur);
}

// Round 8
// 130.793 us; speedup vs baseline: 1.9620x; 1.1841x over previous
//
#include <hip/hip_runtime.h>
#include <hip/hip_bf16.h>
#include <math.h>

#define N_NODES 50000
#define N_EDGES 800000
#define CAP 32          // bucket row = 32 ushorts = exactly one 64B line
#define MAX_OVF 8192    // overflow list; P(deg>32)~1e-4 -> ~5 nodes, ~50 edges

// Two-phase binning:
#define NBIN 196                    // ceil(N_NODES/256) coarse bins of 256 nodes
#define KA_BLOCKS 256               // binning blocks
#define EPB (N_EDGES / KA_BLOCKS)   // 3125 edges per block (exact)
#define SUBCAP 48                   // per-(bin,block) arena cap: mean 16, sigma 4 -> 8 sigma

#define UV_BLOCKS 256               // MFMA UV-GEMM: 1024 waves, 3125 tiles (~3/wave)
#define W2_BLOCKS 16
#define P1_GRID (KA_BLOCKS + UV_BLOCKS + W2_BLOCKS)

typedef _Float16 f16x8 __attribute__((ext_vector_type(8)));
typedef float f32x4 __attribute__((ext_vector_type(4)));

// ---------------------------------------------------------------------------
// Phase 1 (fused, all independent work):
//   blocks [0,256):     edge binning -> per-(bin,block) arena chunks (LDS
//                       histogram+rank; zero global atomics common path).
//   blocks [256,512):   UV prep as MFMA GEMM (R7 PMC: the readlane+fmac VALU
//                       loop was ~200 VALU/node/lane at VALUBusy 33%, and
//                       VGPR=72 forced W1 re-materialization per node. This
//                       is matmul-shaped work -> matrix cores: 16 MFMAs per
//                       16-node tile, W-fragments built once per wave).
//                       U[i]=(W1a-W1b)x_i+b1 -> f16 ; V[j]=W1b x_j -> f16.
//   blocks [512,528):   W2 -> f16.
// Operand mapping copied verbatim from the VERIFIED node_kernel tile:
//   A: lane m+16q holds A[m][k], k=32s+8q+j ; B: lane m+16q holds B[o][k],
//   o=t*16+m, same k ; D: lane holds D[4q+r][m].
// cur[] poison-base trick: cur[0] untouched = base; cur[16] = ovf cursor;
// cur[32] = arena-overflow force-scan flag.
// ---------------------------------------------------------------------------
__global__ __launch_bounds__(256) void phase1_kernel(
    const float* __restrict__ x, const float* __restrict__ W1,
    const float* __restrict__ b1, const float* __restrict__ W2,
    const int* __restrict__ ei,
    _Float16* __restrict__ Uh, _Float16* __restrict__ Vh,
    _Float16* __restrict__ w2f,
    unsigned* __restrict__ arena, unsigned* __restrict__ cntA,
    unsigned* __restrict__ cur, int2* __restrict__ ovf)
{
    __shared__ unsigned sh_hist[256];
    __shared__ unsigned sh_pack[EPB];        // src | dlow<<16 | bin<<24
    __shared__ unsigned short sh_rank[EPB];  // rank within (block,bin)

    const int blk = blockIdx.x;
    const int tid = threadIdx.x;

    if (blk < KA_BLOCKS) {
        // ---- edge binning ----
        sh_hist[tid] = 0;
        __syncthreads();
        const int e0 = blk * EPB;
        for (int i = tid; i < EPB; i += 256) {
            int s = ei[e0 + i];
            int d = ei[N_EDGES + e0 + i];
            unsigned bin = (unsigned)d >> 8;
            unsigned r = atomicAdd(&sh_hist[bin], 1u);
            sh_pack[i] = (unsigned)s | ((unsigned)(d & 255) << 16) | (bin << 24);
            sh_rank[i] = (unsigned short)r;
        }
        __syncthreads();
        if (tid < NBIN) cntA[tid * KA_BLOCKS + blk] = sh_hist[tid];
        const unsigned base = cur[0];
        for (int i = tid; i < EPB; i += 256) {
            unsigned p = sh_pack[i];
            unsigned r = sh_rank[i];
            unsigned bin = p >> 24;
            if (r < SUBCAP) {
                arena[((size_t)bin * KA_BLOCKS + blk) * SUBCAP + r] = p;
            } else {
                // arena overflow (statistically never): exact fallback
                atomicAdd(&cur[32], 1u);  // force node_kernel to scan ovf
                unsigned o = atomicAdd(&cur[16], 1u) - base;
                int d = (int)(bin * 256 + ((p >> 16) & 255u));
                int s = (int)(p & 0xFFFFu);
                if (o < MAX_OVF) ovf[o] = make_int2(d, s);
            }
        }
    } else if (blk < KA_BLOCKS + UV_BLOCKS) {
        // ---- UV prep via MFMA ----
        const int lane = tid & 63;
        const int m = lane & 15;
        const int q = lane >> 4;
        const int wv  = ((blk - KA_BLOCKS) * 256 + tid) >> 6;   // 0..1023
        const int nwv = UV_BLOCKS * 4;

        // Per-wave B-fragments: Wa = W1a - W1b, Wb = W1b (f16). Built once,
        // reused for ~3 tiles. 64 VGPRs total — no per-node W1 reloads.
        f16x8 wafr[4][2], wbfr[4][2];
#pragma unroll
        for (int t = 0; t < 4; ++t) {
            const float* w1r = W1 + (size_t)(t * 16 + m) * 128;
#pragma unroll
            for (int s = 0; s < 2; ++s) {
                const int c0 = 32 * s + q * 8;
                float4 pa0 = *(const float4*)(w1r + c0);
                float4 pa1 = *(const float4*)(w1r + c0 + 4);
                float4 pb0 = *(const float4*)(w1r + 64 + c0);
                float4 pb1 = *(const float4*)(w1r + 64 + c0 + 4);
                float av[8] = {pa0.x, pa0.y, pa0.z, pa0.w,
                               pa1.x, pa1.y, pa1.z, pa1.w};
                float bv[8] = {pb0.x, pb0.y, pb0.z, pb0.w,
                               pb1.x, pb1.y, pb1.z, pb1.w};
#pragma unroll
                for (int j = 0; j < 8; ++j) {
                    wafr[t][s][j] = (_Float16)(av[j] - bv[j]);
                    wbfr[t][s][j] = (_Float16)bv[j];
                }
            }
        }
        float biasv[4];
#pragma unroll
        for (int t = 0; t < 4; ++t) biasv[t] = b1[t * 16 + m];

        for (int tile = wv; tile < N_NODES / 16; tile += nwv) {   // 3125 exact
            // A-frags: x rows tile*16+m -> f16
            const float* xr = x + (size_t)(tile * 16 + m) * 64 + q * 8;
            f16x8 a[2];
#pragma unroll
            for (int s = 0; s < 2; ++s) {
                float4 x0 = *(const float4*)(xr + 32 * s);
                float4 x1 = *(const float4*)(xr + 32 * s + 4);
                float xv[8] = {x0.x, x0.y, x0.z, x0.w, x1.x, x1.y, x1.z, x1.w};
#pragma unroll
                for (int j = 0; j < 8; ++j) a[s][j] = (_Float16)xv[j];
            }
#pragma unroll
            for (int t = 0; t < 4; ++t) {
                f32x4 au = {0.f, 0.f, 0.f, 0.f};
                f32x4 aw = {0.f, 0.f, 0.f, 0.f};
                au = __builtin_amdgcn_mfma_f32_16x16x32_f16(a[0], wafr[t][0], au, 0, 0, 0);
                au = __builtin_amdgcn_mfma_f32_16x16x32_f16(a[1], wafr[t][1], au, 0, 0, 0);
                aw = __builtin_amdgcn_mfma_f32_16x16x32_f16(a[0], wbfr[t][0], aw, 0, 0, 0);
                aw = __builtin_amdgcn_mfma_f32_16x16x32_f16(a[1], wbfr[t][1], aw, 0, 0, 0);
#pragma unroll
                for (int r = 0; r < 4; ++r) {
                    const size_t row = (size_t)(tile * 16 + 4 * q + r) * 64;
                    Uh[row + t * 16 + m] = (_Float16)(au[r] + biasv[t]);
                    Vh[row + t * 16 + m] = (_Float16)aw[r];
                }
            }
        }
    } else {
        const int i = (blk - KA_BLOCKS - UV_BLOCKS) * 256 + tid;
        if (i < 64 * 64) w2f[i] = (_Float16)W2[i];
    }
}

// ---------------------------------------------------------------------------
// Phase 2: one block per coarse bin, 1024 threads. Thread (part,chunk) drains
// quarter [part*n/4,(part+1)*n/4) of arena chunk 'chunk' (slot ORDER within a
// bucket row is irrelevant for max). Writes exact per-node counts.
// ---------------------------------------------------------------------------
__global__ __launch_bounds__(1024) void bucket_kernel(
    const unsigned* __restrict__ arena, const unsigned* __restrict__ cntA,
    unsigned* __restrict__ counts, unsigned short* __restrict__ buckets,
    unsigned* __restrict__ cur, int2* __restrict__ ovf)
{
    __shared__ unsigned lcnt[256];
    const int bin = blockIdx.x;
    const int tid = threadIdx.x;
    if (tid < 256) lcnt[tid] = 0;
    __syncthreads();

    const unsigned base = cur[0];
    const int chunk = tid & 255;
    const int part  = tid >> 8;                        // 0..3
    unsigned n = cntA[(size_t)bin * KA_BLOCKS + chunk];
    if (n > SUBCAP) n = SUBCAP;                        // excess went to ovf
    const unsigned j0 = (n * (unsigned)part) >> 2;
    const unsigned j1 = (n * (unsigned)(part + 1)) >> 2;
    const unsigned* ch = arena + ((size_t)bin * KA_BLOCKS + chunk) * SUBCAP;

    for (unsigned j = j0; j < j1; ++j) {
        unsigned p = ch[j];
        unsigned dlow = (p >> 16) & 255u;
        unsigned s = p & 0xFFFFu;
        unsigned pos = atomicAdd(&lcnt[dlow], 1u);
        int d = bin * 256 + (int)dlow;
        if (pos < CAP) {
            buckets[(size_t)d * CAP + pos] = (unsigned short)s;
        } else {
            unsigned o = atomicAdd(&cur[16], 1u) - base;
            if (o < MAX_OVF) ovf[o] = make_int2(d, (int)s);
        }
    }
    __syncthreads();
    if (tid < 256) {
        const int node = bin * 256 + tid;
        if (node < N_NODES) counts[node] = lcnt[tid];
    }
}

// ---------------------------------------------------------------------------
// Tile compute (all-f16): h = leaky(u+v) computed in PACKED f16, single-f16
// A and B -> 2 MFMAs per output quadrant. Masked max over rows 4q+r < lim
// accumulates into rm[4]; q-reduction hoisted to the caller.
//   A: lane m+16q holds A[m][k]   B: lane n+16q holds W2[n][k]
//   D: lane holds D[4q+r][lane&15]
// ---------------------------------------------------------------------------
__device__ __forceinline__ void tile_mfma_max(
    const f16x8* __restrict__ uh, const f16x8* __restrict__ vv,
    const _Float16* __restrict__ w2f, int m, int q, int lim,
    float* __restrict__ rm)
{
    f16x8 a[2];
#pragma unroll
    for (int s = 0; s < 2; ++s) {
        f16x8 h  = uh[s] + vv[s];
        f16x8 hs = h * (_Float16)0.01f;          // LeakyReLU = max(h, .01h)
#pragma unroll
        for (int j = 0; j < 8; ++j)
            a[s][j] = (h[j] > hs[j]) ? h[j] : hs[j];
    }
#pragma unroll
    for (int t = 0; t < 4; ++t) {
        const f16x8 b0 = *(const f16x8*)(w2f + (t * 16 + m) * 64 + q * 8);
        const f16x8 b1 = *(const f16x8*)(w2f + (t * 16 + m) * 64 + 32 + q * 8);
        f32x4 acc = {0.f, 0.f, 0.f, 0.f};
        acc = __builtin_amdgcn_mfma_f32_16x16x32_f16(a[0], b0, acc, 0, 0, 0);
        acc = __builtin_amdgcn_mfma_f32_16x16x32_f16(a[1], b1, acc, 0, 0, 0);
        float v = -INFINITY;
#pragma unroll
        for (int r = 0; r < 4; ++r)
            if (4 * q + r < lim) v = fmaxf(v, acc[r]);   // mask garbage rows
        rm[t] = fmaxf(rm[t], v);                 // q-reduce deferred to caller
    }
}

// f16 row gather (U and V share the layout): the 4 q-lanes of one row cover
// a full 64B line per instruction.
__device__ __forceinline__ void load_vh(const _Float16* __restrict__ Vh,
                                        unsigned si, int q, f16x8* vv)
{
    const _Float16* b0 = Vh + (size_t)si * 64 + q * 8;
    vv[0] = *(const f16x8*)b0;
    vv[1] = *(const f16x8*)(b0 + 32);
}

// tanh via hw exp + rcp: ~7 VALU vs libm's ~20+.
__device__ __forceinline__ float fast_tanh(float x)
{
    float xc = fminf(fmaxf(x, -12.f), 12.f);
    float e  = __expf(2.f * xc);
    return 1.f - 2.f * __builtin_amdgcn_rcpf(e + 1.f);
}

// ---------------------------------------------------------------------------
// K3: wave per node, 2-deep software pipeline — R7 structure unchanged
// (all-f16 data, 2-MFMA quadrants, addr-only tile-1 prefetch, deferred
// q-reduction, fast tanh). Grid 1024 @ (256,4).
// ---------------------------------------------------------------------------
__global__ __launch_bounds__(256, 4) void node_kernel(
    const unsigned* __restrict__ counts, const unsigned short* __restrict__ buckets,
    const int2* __restrict__ ovf,
    const _Float16* __restrict__ Uh, const _Float16* __restrict__ Vh,
    const _Float16* __restrict__ w2f, const float* __restrict__ b2,
    float* __restrict__ out, const unsigned* __restrict__ cur)
{
    const int lane = threadIdx.x & 63;
    const int m    = lane & 15;
    const int q    = lane >> 4;
    const int wave = (int)((blockIdx.x * blockDim.x + threadIdx.x) >> 6);
    const int nwav = (int)((gridDim.x * blockDim.x) >> 6);

    const float b2v = b2[lane];
    const unsigned base  = cur[0];
    const unsigned force = cur[32] - base;   // arena-overflow force-scan flag
    const unsigned nou   = cur[16] - base;   // total ovf entries

    // ---- prologue: arm node A fully; arm bkt/cnt for node B ----
    const int nA0 = wave;                        // wave < 4096 < N_NODES
    int pB = nA0 + nwav; if (pB >= N_NODES) pB = N_NODES - 1;

    unsigned cntA = counts[nA0];
    int bktA  = buckets[nA0 * CAP + m];
    int bkt2A = buckets[nA0 * CAP + 16 + m];     // same 64B line: free
    f16x8 uhA[2];
    load_vh(Uh, (unsigned)nA0, q, uhA);
    unsigned cntB = counts[pB];
    int bktB  = buckets[pB * CAP + m];
    int bkt2B = buckets[pB * CAP + 16 + m];

    f16x8 vA[2];
    {
        unsigned usiA = (unsigned)bktA;
        if (usiA >= N_NODES) usiA = N_NODES - 1;   // poison-safe clamp
        load_vh(Vh, usiA, q, vA);
    }
    f16x8 uhB[2];
    load_vh(Uh, (unsigned)pB, q, uhB);

    for (int n = nA0; n < N_NODES; n += nwav) {
        int pC = n + 2 * nwav; if (pC >= N_NODES) pC = N_NODES - 1;

        // (1) issue V for node B (bktB arrived during previous compute)
        unsigned usiB = (unsigned)bktB;
        if (usiB >= N_NODES) usiB = N_NODES - 1;
        f16x8 vB[2];
        load_vh(Vh, usiB, q, vB);

        // (2) issue bkt/cnt for node C
        unsigned cntC = counts[pC];
        int bktC  = buckets[pC * CAP + m];
        int bkt2C = buckets[pC * CAP + 16 + m];

        // (3) compute node A = n
        const unsigned c = cntA;
        const int deg = (c < CAP) ? (int)c : CAP;

        float rm[4] = {-INFINITY, -INFINITY, -INFINITY, -INFINITY};
        const int lim0 = (deg < 16) ? deg : 16;
        tile_mfma_max(uhA, vA, w2f, m, q, lim0, rm);      // tile 0 (pre-armed)

        if (deg > 16) {                                   // tile 1: addr pre-armed
            unsigned si2 = (unsigned)bkt2A;               // entry 16+m; garbage
            if (si2 >= N_NODES) si2 = N_NODES - 1;        // rows masked by lim
            f16x8 v2[2];
            load_vh(Vh, si2, q, v2);
            tile_mfma_max(uhA, v2, w2f, m, q, deg - 16, rm);
        }

        if (c > CAP || force != 0u) {   // exact-correctness fallback
            int no = (nou < MAX_OVF) ? (int)nou : MAX_OVF;
            for (int o = 0; o < no; ++o) {
                const int2 ds = ovf[o];
                if (ds.x != n) continue;
                f16x8 vo[2];
                load_vh(Vh, (unsigned)ds.y, q, vo);
                tile_mfma_max(uhA, vo, w2f, m, q, 16, rm);
            }
        }

        // deferred q-reduction (once per node)
#pragma unroll
        for (int t = 0; t < 4; ++t) {
            rm[t] = fmaxf(rm[t], __shfl_xor(rm[t], 16, 64));
            rm[t] = fmaxf(rm[t], __shfl_xor(rm[t], 32, 64));
        }
        const float sel = (q == 0) ? rm[0] : (q == 1) ? rm[1]
                        : (q == 2) ? rm[2] : rm[3];      // col == lane
        out[(size_t)n * 64 + lane] = (c != 0u) ? fast_tanh(sel + b2v) : 0.f;

        // (4) rotate pipeline state; issue U for next B
        cntA = cntB; cntB = cntC;
        bktB = bktC; bkt2A = bkt2B; bkt2B = bkt2C;
#pragma unroll
        for (int i = 0; i < 2; ++i) { uhA[i] = uhB[i]; vA[i] = vB[i]; }
        load_vh(Uh, (unsigned)pC, q, uhB);               // next iter's B == pC
    }
}

// ---------------------------------------------------------------------------
extern "C" void kernel_launch(void* const* d_in, const int* in_sizes, int n_in,
                              void* d_out, int out_size, void* d_ws, size_t ws_size,
                              hipStream_t stream)
{
    const float* x  = (const float*)d_in[0];
    const int*   ei = (const int*)d_in[1];
    const float* W1 = (const float*)d_in[2];
    const float* b1 = (const float*)d_in[3];
    const float* W2 = (const float*)d_in[4];
    const float* b2 = (const float*)d_in[5];
    float* out = (float*)d_out;

    char* p = (char*)d_ws;
    _Float16* Uh = (_Float16*)p;           p += (size_t)N_NODES * 64 * 2;
    _Float16* Vh = (_Float16*)p;           p += (size_t)N_NODES * 64 * 2;
    unsigned* arena = (unsigned*)p;        p += (size_t)NBIN * KA_BLOCKS * SUBCAP * 4;
    unsigned short* buckets = (unsigned short*)p;
                                           p += (size_t)N_NODES * CAP * 2;
    _Float16* w2f = (_Float16*)p;          p += 64 * 64 * 2;
    unsigned* cntA = (unsigned*)p;         p += (size_t)NBIN * KA_BLOCKS * 4;
    unsigned* counts = (unsigned*)p;       p += (size_t)((N_NODES + 63) / 64) * 64 * 4;
    unsigned* cur = (unsigned*)p;          p += 64 * 4;
    int2* ovf = (int2*)p;                  p += (size_t)MAX_OVF * 8;

    phase1_kernel<<<P1_GRID, 256, 0, stream>>>(x, W1, b1, W2, ei,
                                               Uh, Vh, w2f,
                                               arena, cntA, cur, ovf);
    bucket_kernel<<<NBIN, 1024, 0, stream>>>(arena, cntA, counts, buckets, cur, ovf);
    node_kernel<<<1024, 256, 0, stream>>>(counts, buckets, ovf,
                                          Uh, Vh, w2f, b2, out, cur);
}